// Round 2
// baseline (94.545 us; speedup 1.0000x reference)
//
#include <hip/hip_runtime.h>
#include <hip/hip_bf16.h>
#include <math.h>

#define NSTEPS 2
#define NSYMS 2048

// ---------------------------------------------------------------------------
// Prep: compose C = W3 @ W2 @ W1 where Wi = tanh(w_hat_i) * sigmoid(m_hat_i).
// Writes 8 floats to ws: C[0][0..2], C[1][0..2], gb[0], gb[1].
// One block of 64 threads (1 wave). ~336 tanh/sigmoid evals parallelized.
// ---------------------------------------------------------------------------
__global__ __launch_bounds__(64) void prep_kernel(
    const float* __restrict__ gb,
    const float* __restrict__ w1, const float* __restrict__ m1,
    const float* __restrict__ w2, const float* __restrict__ m2,
    const float* __restrict__ w3, const float* __restrict__ m3,
    float* __restrict__ ws)
{
    __shared__ float W1[48];      // [16][3] row-major
    __shared__ float W2[256];     // [16][16] row-major
    __shared__ float W3[32];      // [2][16] row-major
    __shared__ float M[32];       // [2][16] row-major

    const int t = threadIdx.x;

    // Elementwise weight construction: W = tanh(w_hat) * sigmoid(m_hat)
    if (t < 48)
        W1[t] = tanhf(w1[t]) * (1.0f / (1.0f + expf(-m1[t])));
    for (int i = t; i < 256; i += 64)
        W2[i] = tanhf(w2[i]) * (1.0f / (1.0f + expf(-m2[i])));
    if (t < 32)
        W3[t] = tanhf(w3[t]) * (1.0f / (1.0f + expf(-m3[t])));
    __syncthreads();

    // M = W3 @ W2   (2 x 16)
    if (t < 32) {
        const int r = t >> 4, c = t & 15;
        float s = 0.0f;
        #pragma unroll
        for (int k = 0; k < 16; ++k) s += W3[r * 16 + k] * W2[k * 16 + c];
        M[r * 16 + c] = s;
    }
    __syncthreads();

    // C = M @ W1    (2 x 3) -> ws[0..5]
    if (t < 6) {
        const int r = (t < 3) ? 0 : 1, c = (t < 3) ? t : (t - 3);
        float s = 0.0f;
        #pragma unroll
        for (int k = 0; k < 16; ++k) s += M[r * 16 + k] * W1[k * 3 + c];
        ws[t] = s;
    }
    if (t < 2) ws[6 + t] = gb[t];
}

// ---------------------------------------------------------------------------
// Fill: y[t,a,b,c] = gb[c] + C[c,0]*(t/2) + C[c,1]*(a/2048) + C[c,2]*(b/2048)
// Output layout [t][a][b][c], c (size 2) fastest. One float4 per thread-iter
// = {b,c0},{b,c1},{b+1,c0},{b+1,c1} — coalesced 16 B/lane stores.
// Grid 2048x256 grid-stride -> exactly 8 float4 (128 B) per thread.
// ---------------------------------------------------------------------------
__global__ __launch_bounds__(256) void fill_kernel(
    const float* __restrict__ ws, float4* __restrict__ out)
{
    const float C00 = ws[0], C01 = ws[1], C02 = ws[2];
    const float C10 = ws[3], C11 = ws[4], C12 = ws[5];
    const float g0  = ws[6], g1  = ws[7];

    const int PAIRS = NSYMS / 2;                    // 1024 float4 per (t,a) row
    const int total = NSTEPS * NSYMS * PAIRS;       // 4,194,304 float4
    const int stride = gridDim.x * blockDim.x;

    const float invN = 1.0f / (float)NSYMS;

    for (int idx = blockIdx.x * blockDim.x + threadIdx.x; idx < total; idx += stride) {
        const int bp    = idx & (PAIRS - 1);        // b pair index   (10 bits)
        const int ta    = idx >> 10;
        const int a     = ta & (NSYMS - 1);         // a              (11 bits)
        const int tstep = ta >> 11;                 // t              (1 bit)

        const float tf = (float)tstep * 0.5f;
        const float af = (float)a * invN;
        const float b0 = (float)(bp << 1) * invN;
        const float b1 = b0 + invN;

        const float base0 = g0 + C00 * tf + C01 * af;
        const float base1 = g1 + C10 * tf + C11 * af;

        float4 v;
        v.x = base0 + C02 * b0;
        v.y = base1 + C12 * b0;
        v.z = base0 + C02 * b1;
        v.w = base1 + C12 * b1;
        out[idx] = v;
    }
}

extern "C" void kernel_launch(void* const* d_in, const int* in_sizes, int n_in,
                              void* d_out, int out_size, void* d_ws, size_t ws_size,
                              hipStream_t stream) {
    // Input order: market, gb, w_hat1, m_hat1, w_hat2, m_hat2, w_hat3, m_hat3.
    // market (d_in[0]) is unused by the reference (only its shape matters).
    const float* gb = (const float*)d_in[1];
    const float* w1 = (const float*)d_in[2];
    const float* m1 = (const float*)d_in[3];
    const float* w2 = (const float*)d_in[4];
    const float* m2 = (const float*)d_in[5];
    const float* w3 = (const float*)d_in[6];
    const float* m3 = (const float*)d_in[7];

    float*  ws  = (float*)d_ws;
    float4* out = (float4*)d_out;

    prep_kernel<<<1, 64, 0, stream>>>(gb, w1, m1, w2, m2, w3, m3, ws);

    // 64 MB of stores; 2048 blocks x 256 threads, 8 float4 per thread.
    fill_kernel<<<2048, 256, 0, stream>>>(ws, out);
}

// Round 3
// 93.947 us; speedup vs baseline: 1.0064x; 1.0064x over previous
//
#include <hip/hip_runtime.h>
#include <hip/hip_bf16.h>
#include <math.h>

#define NSTEPS 2
#define NSYMS 2048

// ---------------------------------------------------------------------------
// Single fused kernel.
//
// Algebra: each NAC layer is y = x @ W.T with W = tanh(W_hat)*sigmoid(M_hat)
// applied to WEIGHTS only, so the 3 layers compose to one affine map:
//   y[t,a,b,c] = gb[c] + C[c,0]*(t/2) + C[c,1]*(a/2048) + C[c,2]*(b/2048)
// with C = W3 @ W2 @ W1 (2x3). `market` is never read by the reference.
//
// Every block redundantly computes C in LDS (~336 transcendentals spread over
// 256 threads + two tiny matmuls, ~1-2 us prologue, fully overlapped since all
// 2048 blocks are co-resident), then streams its share of the 64 MiB output
// as coalesced float4 stores (c fastest, 2 b-values per float4).
// ---------------------------------------------------------------------------
__global__ __launch_bounds__(256) void fused_fill_kernel(
    const float* __restrict__ gb,
    const float* __restrict__ w1, const float* __restrict__ m1,
    const float* __restrict__ w2, const float* __restrict__ m2,
    const float* __restrict__ w3, const float* __restrict__ m3,
    float4* __restrict__ out)
{
    __shared__ float W1[48];      // [16][3]
    __shared__ float W2[256];     // [16][16]
    __shared__ float W3[32];      // [2][16]
    __shared__ float M[32];       // [2][16]
    __shared__ float Cs[8];       // C[0][0..2], C[1][0..2], gb[0], gb[1]

    const int t = threadIdx.x;

    // W = tanh(w_hat) * sigmoid(m_hat), elementwise
    if (t < 48)  W1[t] = tanhf(w1[t]) * (1.0f / (1.0f + expf(-m1[t])));
    W2[t] = tanhf(w2[t]) * (1.0f / (1.0f + expf(-m2[t])));   // all 256 threads
    if (t < 32)  W3[t] = tanhf(w3[t]) * (1.0f / (1.0f + expf(-m3[t])));
    __syncthreads();

    // M = W3 @ W2   (2 x 16)
    if (t < 32) {
        const int r = t >> 4, c = t & 15;
        float s = 0.0f;
        #pragma unroll
        for (int k = 0; k < 16; ++k) s += W3[r * 16 + k] * W2[k * 16 + c];
        M[r * 16 + c] = s;
    }
    __syncthreads();

    // C = M @ W1    (2 x 3)
    if (t < 6) {
        const int r = (t < 3) ? 0 : 1, c = (t < 3) ? t : (t - 3);
        float s = 0.0f;
        #pragma unroll
        for (int k = 0; k < 16; ++k) s += M[r * 16 + k] * W1[k * 3 + c];
        Cs[t] = s;
    }
    if (t < 2) Cs[6 + t] = gb[t];
    __syncthreads();

    // LDS broadcast reads (same address across wave -> no conflicts)
    const float C00 = Cs[0], C01 = Cs[1], C02 = Cs[2];
    const float C10 = Cs[3], C11 = Cs[4], C12 = Cs[5];
    const float g0  = Cs[6], g1  = Cs[7];

    const int PAIRS  = NSYMS / 2;                   // 1024 float4 per (t,a) row
    const int total  = NSTEPS * NSYMS * PAIRS;      // 4,194,304 float4
    const int stride = gridDim.x * blockDim.x;      // 524,288
    const float invN = 1.0f / (float)NSYMS;

    // Exactly 8 float4 (128 B) per thread; fully coalesced streaming stores.
    for (int idx = blockIdx.x * blockDim.x + t; idx < total; idx += stride) {
        const int bp    = idx & (PAIRS - 1);        // b-pair index (10 bits)
        const int ta    = idx >> 10;
        const int a     = ta & (NSYMS - 1);         // a (11 bits)
        const int tstep = ta >> 11;                 // t (1 bit)

        const float tf = (float)tstep * 0.5f;
        const float af = (float)a * invN;
        const float b0 = (float)(bp << 1) * invN;
        const float b1 = b0 + invN;

        const float base0 = g0 + C00 * tf + C01 * af;
        const float base1 = g1 + C10 * tf + C11 * af;

        float4 v;
        v.x = base0 + C02 * b0;
        v.y = base1 + C12 * b0;
        v.z = base0 + C02 * b1;
        v.w = base1 + C12 * b1;
        out[idx] = v;
    }
}

extern "C" void kernel_launch(void* const* d_in, const int* in_sizes, int n_in,
                              void* d_out, int out_size, void* d_ws, size_t ws_size,
                              hipStream_t stream) {
    // Input order: market, gb, w_hat1, m_hat1, w_hat2, m_hat2, w_hat3, m_hat3.
    // market (d_in[0]) is unused by the reference (only its shape matters).
    const float* gb = (const float*)d_in[1];
    const float* w1 = (const float*)d_in[2];
    const float* m1 = (const float*)d_in[3];
    const float* w2 = (const float*)d_in[4];
    const float* m2 = (const float*)d_in[5];
    const float* w3 = (const float*)d_in[6];
    const float* m3 = (const float*)d_in[7];

    float4* out = (float4*)d_out;

    // 64 MiB of stores; 2048 blocks x 256 threads, 8 float4 per thread.
    fused_fill_kernel<<<2048, 256, 0, stream>>>(gb, w1, m1, w2, m2, w3, m3, out);
}